// Round 13
// baseline (224.625 us; speedup 1.0000x reference)
//
#include <hip/hip_runtime.h>
#include <hip/hip_bf16.h>
#include <hip/hip_cooperative_groups.h>
#include <cstdint>
#include <cstddef>

namespace cg = cooperative_groups;

// Problem constants: B=16, S=2048, E=128, H=768, C=457
constexpr int Bn = 16, Sn = 2048, En = 128, Hn = 768, Cn = 457;
constexpr int NP = 512;                 // padded class dim for logits GEMM
using f32x4  = __attribute__((ext_vector_type(4))) float;
using bf16x8 = __attribute__((ext_vector_type(8))) short;

static __device__ inline unsigned short f2bf(float x) {
  __hip_bfloat16 b = __float2bfloat16(x);
  return *reinterpret_cast<unsigned short*>(&b);
}
static __device__ inline float bflo(unsigned int u) {  // low bf16 -> f32
  unsigned int v = u << 16;
  return *reinterpret_cast<float*>(&v);
}
static __device__ inline float bfhi(unsigned int u) {  // high bf16 -> f32
  unsigned int v = u & 0xFFFF0000u;
  return *reinterpret_cast<float*>(&v);
}

// LDS-only barrier (rule #18 fencing).
#define LGKM_BAR()                                            \
  do {                                                        \
    asm volatile("s_waitcnt lgkmcnt(0)" ::: "memory");        \
    __builtin_amdgcn_sched_barrier(0);                        \
    __builtin_amdgcn_s_barrier();                             \
    __builtin_amdgcn_sched_barrier(0);                        \
  } while (0)

// ---------------------------------------------------------------------------
// Kernel 0: bit-pack entities_list, WORD-MAJOR: pk2[b][w][s], w = e>>5.
// 4096 waves x 8 tokens, unroll 8.  [r8 exact]
// ---------------------------------------------------------------------------
__global__ __launch_bounds__(256) void pack_k(
    const int* __restrict__ el, unsigned int* __restrict__ pk2)
{
  const int l = threadIdx.x & 63;
  const int gw = blockIdx.x * 4 + (threadIdx.x >> 6);   // 4096 waves
  #pragma unroll 8
  for (int j = 0; j < 8; ++j) {
    const int tok = gw * 8 + j;                         // 0 .. 32767
    const int b = tok >> 11, s = tok & 2047;
    const int v0 = el[(size_t)tok * 128 + l];
    const int v1 = el[(size_t)tok * 128 + 64 + l];
    const unsigned long long b0 = __ballot(v0 != 0);
    const unsigned long long b1 = __ballot(v1 != 0);
    if (l == 0) {
      unsigned int* p = pk2 + (size_t)b * 4 * Sn + s;
      p[0]          = (unsigned int)b0;
      p[Sn]         = (unsigned int)(b0 >> 32);
      p[2 * Sn]     = (unsigned int)b1;
      p[3 * Sn]     = (unsigned int)(b1 >> 32);
    }
  }
}

// ---------------------------------------------------------------------------
// Kernel 1: pooling bmm.  [r12 exact]
// ---------------------------------------------------------------------------
constexpr int PBN = 32, PBK2 = 64, PLD2 = 72;   // Bs row stride 144B
constexpr int SCH = 4, SLEN = Sn / SCH, PNK2 = SLEN / PBK2;   // 8 steps
__global__ __launch_bounds__(256, 6) void pool_k(
    const float* __restrict__ hidden,       // (B,S,H)
    const unsigned int* __restrict__ pk2,   // (B,4,S) packed membership
    unsigned short* __restrict__ entp)      // (SCH, B*E, H) bf16 partials
{
  const int b = blockIdx.x, n0 = blockIdx.y * PBN, sc = blockIdx.z;
  const int s0 = sc * SLEN;
  const int tid = threadIdx.x, l = tid & 63, wv = tid >> 6;  // 4 waves
  const int wm = wv >> 1, wn = wv & 1;                       // 2 x 2

  __shared__ unsigned short Bs[2][PBN][PLD2];  // 9.2 KB  (h x s)
  __shared__ unsigned int   PK2[4 * SLEN];     // 8 KB (word-major slice)

  {
    const int w = tid >> 6, off = (tid & 63) * 8;
    const unsigned int* srcp =
        pk2 + (size_t)b * 4 * Sn + (size_t)w * Sn + s0 + off;
    *reinterpret_cast<uint4*>(&PK2[w * SLEN + off]) =
        *reinterpret_cast<const uint4*>(srcp);
    *reinterpret_cast<uint4*>(&PK2[w * SLEN + off + 4]) =
        *reinterpret_cast<const uint4*>(srcp + 4);
  }

  const float* hb = hidden + ((size_t)b * Sn + s0) * Hn + n0;
  const int g = wv * 2 + (l >> 5), col = l & 31;   // 8 token-groups x 32 cols

  auto loadh = [&](int kk, float (&f)[8]) {
    const int sb = kk * PBK2 + g * 8;
    #pragma unroll
    for (int i = 0; i < 8; ++i)
      f[i] = hb[(size_t)(sb + i) * Hn + col];
  };

  auto stage_b = [&](int bsel, const float (&f)[8]) {
    uint2 d0, d1;
    d0.x = (unsigned int)f2bf(f[0]) | ((unsigned int)f2bf(f[1]) << 16);
    d0.y = (unsigned int)f2bf(f[2]) | ((unsigned int)f2bf(f[3]) << 16);
    d1.x = (unsigned int)f2bf(f[4]) | ((unsigned int)f2bf(f[5]) << 16);
    d1.y = (unsigned int)f2bf(f[6]) | ((unsigned int)f2bf(f[7]) << 16);
    *reinterpret_cast<uint2*>(&Bs[bsel][col][g * 8])     = d0;
    *reinterpret_cast<uint2*>(&Bs[bsel][col][g * 8 + 4]) = d1;
  };

  f32x4 acc[4] = {};
  const int rl = l & 15, q = l >> 4, kr = q * 8;

  auto mfma_step = [&](int k, int cur) {
    #pragma unroll
    for (int ks = 0; ks < 2; ++ks) {       // two 32-token sub-steps
      const int sbase = k * PBK2 + ks * 32 + kr;
      const bf16x8 bfr = *reinterpret_cast<const bf16x8*>(
          &Bs[cur][wn * 16 + rl][ks * 32 + kr]);
      #pragma unroll
      for (int mp = 0; mp < 2; ++mp) {     // word shared by mi pair
        const int w = wm * 2 + mp;
        const uint4 u0 = *reinterpret_cast<const uint4*>(&PK2[w * SLEN + sbase]);
        const uint4 u1 = *reinterpret_cast<const uint4*>(&PK2[w * SLEN + sbase + 4]);
        #pragma unroll
        for (int mh = 0; mh < 2; ++mh) {   // mi = mp*2 + mh
          const int bi = mh * 16 + rl;
          bf16x8 afr;
          unsigned int* ap = reinterpret_cast<unsigned int*>(&afr);
          ap[0] = (((u0.x >> bi) & 1u) ? 0x3F80u : 0u) |
                  (((u0.y >> bi) & 1u) ? 0x3F800000u : 0u);
          ap[1] = (((u0.z >> bi) & 1u) ? 0x3F80u : 0u) |
                  (((u0.w >> bi) & 1u) ? 0x3F800000u : 0u);
          ap[2] = (((u1.x >> bi) & 1u) ? 0x3F80u : 0u) |
                  (((u1.y >> bi) & 1u) ? 0x3F800000u : 0u);
          ap[3] = (((u1.z >> bi) & 1u) ? 0x3F80u : 0u) |
                  (((u1.w >> bi) & 1u) ? 0x3F800000u : 0u);
          acc[mp * 2 + mh] = __builtin_amdgcn_mfma_f32_16x16x32_bf16(
              afr, bfr, acc[mp * 2 + mh], 0, 0, 0);
        }
      }
    }
  };

  float pf[3][8];
  loadh(0, pf[0]);
  loadh(1, pf[1]);
  LGKM_BAR();                    // PK2 visible (global loads stay in flight)
  stage_b(0, pf[0]);
  LGKM_BAR();

  #pragma unroll
  for (int k = 0; k < PNK2; ++k) {
    if (k + 2 < PNK2) loadh(k + 2, pf[(k + 2) % 3]);
    mfma_step(k, k & 1);
    if (k + 1 < PNK2) {
      stage_b((k + 1) & 1, pf[(k + 1) % 3]);
      LGKM_BAR();
    }
  }

  unsigned short* dst = entp + (size_t)sc * Bn * En * Hn;
  const int rg = q * 4;
  const int colo = n0 + wn * 16 + rl;
  #pragma unroll
  for (int mi = 0; mi < 4; ++mi) {
    #pragma unroll
    for (int r = 0; r < 4; ++r) {
      const int e = wm * 64 + mi * 16 + rg + r;
      dst[(size_t)(b * En + e) * Hn + colo] = f2bf(acc[mi][r]);
    }
  }
}

// ---------------------------------------------------------------------------
// Kernel 2 (cooperative): fused tail = finalize+Wcast | gemm | ce | reduce,
// separated by grid.sync(). 512 blocks x 256 threads (2/CU, co-resident).
// Each phase keeps its previous code/indexing -> bit-identical results.
// ---------------------------------------------------------------------------
constexpr int BM = 64, BN = 32, BK = 32, LDP = BK + 24;   // 112B row stride
__global__ __launch_bounds__(256) void tail_k(
    const unsigned short* __restrict__ entp,  // (SCH,B*E,H) bf16 partials
    const int* __restrict__ elen,             // (B,E)
    const float* __restrict__ Wm,             // (457,768) f32
    const float* __restrict__ bv,             // (457)
    const int* __restrict__ attr,             // (B,E)
    const unsigned char* __restrict__ emask,  // (B,E)
    unsigned short* __restrict__ entbf,       // (B*E,H) bf16
    unsigned short* __restrict__ wbf,         // (512,768) bf16
    float* __restrict__ logits,               // (2048,512) f32
    float* __restrict__ nll,                  // (2048)
    float* __restrict__ out)                  // (1)
{
  cg::grid_group grid = cg::this_grid();
  const int bid = blockIdx.x, tid = threadIdx.x;

  __shared__ unsigned short As[BM][LDP];
  __shared__ unsigned short Bs2[BN][LDP];
  __shared__ float ws_[4], wc_[4];

  // ---- Phase A: finalize (2048 rows) + W cast (512 rows), block-stride ----
  for (int task = bid; task < Bn * En + NP; task += 512) {
    if (task < Bn * En) {
      const float inv = 1.0f / (float)elen[task];
      constexpr size_t PSu = (size_t)Bn * En * Hn / 2;
      const unsigned int* src =
          reinterpret_cast<const unsigned int*>(entp) + (size_t)task * (Hn / 2);
      unsigned int* dst =
          reinterpret_cast<unsigned int*>(entbf) + (size_t)task * (Hn / 2);
      for (int t = tid; t < Hn / 2; t += 256) {
        float lo = 0.f, hi = 0.f;
        #pragma unroll
        for (int p = 0; p < SCH; ++p) {
          const unsigned int u = src[t + p * PSu];
          lo += bflo(u);
          hi += bfhi(u);
        }
        dst[t] = (unsigned int)f2bf(lo * inv) |
                 ((unsigned int)f2bf(hi * inv) << 16);
      }
    } else {
      const int c = task - Bn * En;                  // 0..511
      unsigned int* dst =
          reinterpret_cast<unsigned int*>(wbf) + (size_t)c * (Hn / 2);
      for (int t = tid; t < Hn / 2; t += 256) {
        unsigned int o = 0u;
        if (c < Cn) {
          const float* wp = Wm + (size_t)c * Hn + 2 * t;
          o = (unsigned int)f2bf(wp[0]) | ((unsigned int)f2bf(wp[1]) << 16);
        }
        dst[t] = o;
      }
    }
  }
  grid.sync();

  // ---- Phase B: logits GEMM, one 64x32 tile per block (512 tiles) ----
  {
    const int bm = bid >> 4, bn = bid & 15;
    const int lane = tid & 63, wv = tid >> 6;
    const int wm = wv >> 1, wn = wv & 1;            // 2x2 wave grid
    f32x4 acc[2] = {};

    for (int k0 = 0; k0 < Hn; k0 += BK) {
      {
        const int r = tid >> 2, kc = (tid & 3) * 8;
        const unsigned short* src = entbf + (size_t)(bm * BM + r) * Hn + k0 + kc;
        *reinterpret_cast<ulonglong2*>(&As[r][kc]) =
            *reinterpret_cast<const ulonglong2*>(src);
      }
      if (tid < 128) {
        const int r = tid >> 2, kc = (tid & 3) * 8;
        const unsigned short* src = wbf + (size_t)(bn * BN + r) * Hn + k0 + kc;
        *reinterpret_cast<ulonglong2*>(&Bs2[r][kc]) =
            *reinterpret_cast<const ulonglong2*>(src);
      }
      __syncthreads();

      const int kr = (lane >> 4) * 8, rl = lane & 15;
      const bf16x8 bf = *reinterpret_cast<const bf16x8*>(&Bs2[wn * 16 + rl][kr]);
      #pragma unroll
      for (int mi = 0; mi < 2; ++mi) {
        const bf16x8 af =
            *reinterpret_cast<const bf16x8*>(&As[wm * 32 + mi * 16 + rl][kr]);
        acc[mi] = __builtin_amdgcn_mfma_f32_16x16x32_bf16(af, bf, acc[mi], 0, 0, 0);
      }
      __syncthreads();
    }

    const int cl = lane & 15, rg = (lane >> 4) * 4;
    const int colo = bn * BN + wn * 16 + cl;
    #pragma unroll
    for (int mi = 0; mi < 2; ++mi) {
      #pragma unroll
      for (int r = 0; r < 4; ++r) {
        const int row = bm * BM + wm * 32 + mi * 16 + rg + r;
        logits[(size_t)row * NP + colo] = acc[mi][r];
      }
    }
  }
  grid.sync();

  // ---- Phase C: CE per entity (4 rows/block, one wave each) ----
  {
    const int wv = tid >> 6, lane = tid & 63;
    const int be = bid * 4 + wv;
    if (emask[be]) {
      const float* row = logits + (size_t)be * NP;
      float mx = -3.4e38f;
      for (int i = lane; i < Cn; i += 64) mx = fmaxf(mx, row[i] + bv[i]);
      #pragma unroll
      for (int o = 32; o; o >>= 1) mx = fmaxf(mx, __shfl_xor(mx, o, 64));
      float sm = 0.f;
      for (int i = lane; i < Cn; i += 64) sm += __expf(row[i] + bv[i] - mx);
      #pragma unroll
      for (int o = 32; o; o >>= 1) sm += __shfl_xor(sm, o, 64);
      if (lane == 0) {
        const int tg = attr[be];
        nll[be] = mx + logf(sm) - (row[tg] + bv[tg]);
      }
    } else if (lane == 0) {
      nll[be] = 0.f;
    }
  }
  grid.sync();

  // ---- Phase D: final reduction (block 0 only) ----
  if (bid == 0) {
    float s = 0.f, c = 0.f;
    for (int i = tid; i < Bn * En; i += 256) {
      s += nll[i];
      c += (float)emask[i];
    }
    #pragma unroll
    for (int o = 32; o; o >>= 1) {
      s += __shfl_xor(s, o, 64);
      c += __shfl_xor(c, o, 64);
    }
    const int wave = tid >> 6, lane = tid & 63;
    if (lane == 0) { ws_[wave] = s; wc_[wave] = c; }
    __syncthreads();
    if (tid == 0) {
      out[0] = (ws_[0] + ws_[1] + ws_[2] + ws_[3]) /
               (wc_[0] + wc_[1] + wc_[2] + wc_[3]);
    }
  }
}

// ---------------------------------------------------------------------------
extern "C" void kernel_launch(void* const* d_in, const int* in_sizes, int n_in,
                              void* d_out, int out_size, void* d_ws, size_t ws_size,
                              hipStream_t stream) {
  const float* hidden        = (const float*)d_in[0];
  const int* attr            = (const int*)d_in[3];
  const int* el              = (const int*)d_in[4];
  const int* elen            = (const int*)d_in[5];
  const unsigned char* emask = (const unsigned char*)d_in[6];
  const float* Wm            = (const float*)d_in[7];
  const float* bv            = (const float*)d_in[8];

  unsigned short* entbf = (unsigned short*)d_ws;            // 2048*768 bf16
  unsigned short* wbf   = entbf + (size_t)Bn * En * Hn;     // 512*768 bf16
  float* logits = (float*)(wbf + (size_t)NP * Hn);          // 2048*512 f32
  float* nll    = logits + (size_t)Bn * En * NP;            // 2048 f32
  unsigned int* pk2buf = (unsigned int*)(nll + Bn * En);    // B*4*S u32
  unsigned short* entp =
      (unsigned short*)(pk2buf + (size_t)Bn * 4 * Sn);      // SCH*2048*768 bf16
  float* outp = (float*)d_out;

  hipLaunchKernelGGL(pack_k, dim3(1024), dim3(256), 0, stream, el, pk2buf);
  hipLaunchKernelGGL(pool_k, dim3(Bn, Hn / PBN, SCH), dim3(256), 0, stream,
                     hidden, pk2buf, entp);

  void* args[] = {(void*)&entp, (void*)&elen, (void*)&Wm, (void*)&bv,
                  (void*)&attr, (void*)&emask, (void*)&entbf, (void*)&wbf,
                  (void*)&logits, (void*)&nll, (void*)&outp};
  hipLaunchCooperativeKernel((const void*)tail_k, dim3(512), dim3(256),
                             args, 0, stream);
}

// Round 14
// 69.769 us; speedup vs baseline: 3.2195x; 3.2195x over previous
//
#include <hip/hip_runtime.h>
#include <hip/hip_bf16.h>
#include <cstdint>
#include <cstddef>

// Problem constants: B=16, S=2048, E=128, H=768, C=457
constexpr int Bn = 16, Sn = 2048, En = 128, Hn = 768, Cn = 457;
constexpr int NP = 512;                 // padded class dim
using f32x4  = __attribute__((ext_vector_type(4))) float;
using bf16x8 = __attribute__((ext_vector_type(8))) short;

static __device__ inline unsigned int f2bf(float x) {
  __hip_bfloat16 b = __float2bfloat16(x);
  return (unsigned int)*reinterpret_cast<unsigned short*>(&b);
}
static __device__ inline float bflo(unsigned int u) {
  unsigned int v = u << 16;
  return *reinterpret_cast<float*>(&v);
}
static __device__ inline float bfhi(unsigned int u) {
  unsigned int v = u & 0xFFFF0000u;
  return *reinterpret_cast<float*>(&v);
}

// LDS-only barrier (rule #18 fencing).
#define LGKM_BAR()                                            \
  do {                                                        \
    asm volatile("s_waitcnt lgkmcnt(0)" ::: "memory");        \
    __builtin_amdgcn_sched_barrier(0);                        \
    __builtin_amdgcn_s_barrier();                             \
    __builtin_amdgcn_sched_barrier(0);                        \
  } while (0)

// ---------------------------------------------------------------------------
// Kernel 0: bit-pack entities_list (word-major pk2[b][w][s]) + piggybacked
// W f32->bf16 cast (blocks 0..511 each cast one W row; rows >=457 zeroed).
// ---------------------------------------------------------------------------
__global__ __launch_bounds__(256) void pack_k(
    const int* __restrict__ el, const float* __restrict__ Wm,
    unsigned int* __restrict__ pk2, unsigned short* __restrict__ wbf)
{
  const int l = threadIdx.x & 63;
  const int gw = blockIdx.x * 4 + (threadIdx.x >> 6);   // 4096 waves
  #pragma unroll 8
  for (int j = 0; j < 8; ++j) {
    const int tok = gw * 8 + j;                         // 0 .. 32767
    const int b = tok >> 11, s = tok & 2047;
    const int v0 = el[(size_t)tok * 128 + l];
    const int v1 = el[(size_t)tok * 128 + 64 + l];
    const unsigned long long b0 = __ballot(v0 != 0);
    const unsigned long long b1 = __ballot(v1 != 0);
    if (l == 0) {
      unsigned int* p = pk2 + (size_t)b * 4 * Sn + s;
      p[0]          = (unsigned int)b0;
      p[Sn]         = (unsigned int)(b0 >> 32);
      p[2 * Sn]     = (unsigned int)b1;
      p[3 * Sn]     = (unsigned int)(b1 >> 32);
    }
  }
  // piggyback: W cast, one row per block (blocks 0..511)
  const int c = blockIdx.x;
  if (c < NP) {
    unsigned int* dst = reinterpret_cast<unsigned int*>(wbf) + (size_t)c * (Hn / 2);
    for (int t = threadIdx.x; t < Hn / 2; t += 256) {
      unsigned int o = 0u;
      if (c < Cn) {
        const float* wp = Wm + (size_t)c * Hn + 2 * t;
        o = f2bf(wp[0]) | (f2bf(wp[1]) << 16);
      }
      dst[t] = o;
    }
  }
}

// ---------------------------------------------------------------------------
// Kernel 1: pooling bmm.  [r12 exact]
// ---------------------------------------------------------------------------
constexpr int PBN = 32, PBK2 = 64, PLD2 = 72;   // Bs row stride 144B
constexpr int SCH = 4, SLEN = Sn / SCH, PNK2 = SLEN / PBK2;   // 8 steps
__global__ __launch_bounds__(256, 6) void pool_k(
    const float* __restrict__ hidden,       // (B,S,H)
    const unsigned int* __restrict__ pk2,   // (B,4,S) packed membership
    unsigned short* __restrict__ entp)      // (SCH, B*E, H) bf16 partials
{
  const int b = blockIdx.x, n0 = blockIdx.y * PBN, sc = blockIdx.z;
  const int s0 = sc * SLEN;
  const int tid = threadIdx.x, l = tid & 63, wv = tid >> 6;  // 4 waves
  const int wm = wv >> 1, wn = wv & 1;                       // 2 x 2

  __shared__ unsigned short Bs[2][PBN][PLD2];  // 9.2 KB  (h x s)
  __shared__ unsigned int   PK2[4 * SLEN];     // 8 KB (word-major slice)

  {
    const int w = tid >> 6, off = (tid & 63) * 8;
    const unsigned int* srcp =
        pk2 + (size_t)b * 4 * Sn + (size_t)w * Sn + s0 + off;
    *reinterpret_cast<uint4*>(&PK2[w * SLEN + off]) =
        *reinterpret_cast<const uint4*>(srcp);
    *reinterpret_cast<uint4*>(&PK2[w * SLEN + off + 4]) =
        *reinterpret_cast<const uint4*>(srcp + 4);
  }

  const float* hb = hidden + ((size_t)b * Sn + s0) * Hn + n0;
  const int g = wv * 2 + (l >> 5), col = l & 31;   // 8 token-groups x 32 cols

  auto loadh = [&](int kk, float (&f)[8]) {
    const int sb = kk * PBK2 + g * 8;
    #pragma unroll
    for (int i = 0; i < 8; ++i)
      f[i] = hb[(size_t)(sb + i) * Hn + col];
  };

  auto stage_b = [&](int bsel, const float (&f)[8]) {
    uint2 d0, d1;
    d0.x = f2bf(f[0]) | (f2bf(f[1]) << 16);
    d0.y = f2bf(f[2]) | (f2bf(f[3]) << 16);
    d1.x = f2bf(f[4]) | (f2bf(f[5]) << 16);
    d1.y = f2bf(f[6]) | (f2bf(f[7]) << 16);
    *reinterpret_cast<uint2*>(&Bs[bsel][col][g * 8])     = d0;
    *reinterpret_cast<uint2*>(&Bs[bsel][col][g * 8 + 4]) = d1;
  };

  f32x4 acc[4] = {};
  const int rl = l & 15, q = l >> 4, kr = q * 8;

  auto mfma_step = [&](int k, int cur) {
    #pragma unroll
    for (int ks = 0; ks < 2; ++ks) {       // two 32-token sub-steps
      const int sbase = k * PBK2 + ks * 32 + kr;
      const bf16x8 bfr = *reinterpret_cast<const bf16x8*>(
          &Bs[cur][wn * 16 + rl][ks * 32 + kr]);
      #pragma unroll
      for (int mp = 0; mp < 2; ++mp) {     // word shared by mi pair
        const int w = wm * 2 + mp;
        const uint4 u0 = *reinterpret_cast<const uint4*>(&PK2[w * SLEN + sbase]);
        const uint4 u1 = *reinterpret_cast<const uint4*>(&PK2[w * SLEN + sbase + 4]);
        #pragma unroll
        for (int mh = 0; mh < 2; ++mh) {   // mi = mp*2 + mh
          const int bi = mh * 16 + rl;
          bf16x8 afr;
          unsigned int* ap = reinterpret_cast<unsigned int*>(&afr);
          ap[0] = (((u0.x >> bi) & 1u) ? 0x3F80u : 0u) |
                  (((u0.y >> bi) & 1u) ? 0x3F800000u : 0u);
          ap[1] = (((u0.z >> bi) & 1u) ? 0x3F80u : 0u) |
                  (((u0.w >> bi) & 1u) ? 0x3F800000u : 0u);
          ap[2] = (((u1.x >> bi) & 1u) ? 0x3F80u : 0u) |
                  (((u1.y >> bi) & 1u) ? 0x3F800000u : 0u);
          ap[3] = (((u1.z >> bi) & 1u) ? 0x3F80u : 0u) |
                  (((u1.w >> bi) & 1u) ? 0x3F800000u : 0u);
          acc[mp * 2 + mh] = __builtin_amdgcn_mfma_f32_16x16x32_bf16(
              afr, bfr, acc[mp * 2 + mh], 0, 0, 0);
        }
      }
    }
  };

  float pf[3][8];
  loadh(0, pf[0]);
  loadh(1, pf[1]);
  LGKM_BAR();                    // PK2 visible (global loads stay in flight)
  stage_b(0, pf[0]);
  LGKM_BAR();

  #pragma unroll
  for (int k = 0; k < PNK2; ++k) {
    if (k + 2 < PNK2) loadh(k + 2, pf[(k + 2) % 3]);
    mfma_step(k, k & 1);
    if (k + 1 < PNK2) {
      stage_b((k + 1) & 1, pf[(k + 1) % 3]);
      LGKM_BAR();
    }
  }

  unsigned short* dst = entp + (size_t)sc * Bn * En * Hn;
  const int rg = q * 4;
  const int colo = n0 + wn * 16 + rl;
  #pragma unroll
  for (int mi = 0; mi < 4; ++mi) {
    #pragma unroll
    for (int r = 0; r < 4; ++r) {
      const int e = wm * 64 + mi * 16 + rg + r;
      dst[(size_t)(b * En + e) * Hn + colo] = (unsigned short)f2bf(acc[mi][r]);
    }
  }
}

// ---------------------------------------------------------------------------
// Kernel 2: fused tail, block-local (NO grid sync). Each block owns 16
// entity rows: finalize partials -> LDS A-tile (bf16), GEMM 16x512 vs wbf
// (per-fragment direct loads, no B staging), logits -> LDS, CE in-block.
// 128 blocks x 256 threads. Bit-identical math to the r12 split kernels.
// ---------------------------------------------------------------------------
__global__ __launch_bounds__(256) void tail16_k(
    const unsigned short* __restrict__ entp,  // (SCH,B*E,H) bf16 partials
    const int* __restrict__ elen,             // (B,E)
    const unsigned short* __restrict__ wbf,   // (512,768) bf16
    const float* __restrict__ bv,             // (457)
    const int* __restrict__ attr,             // (B,E)
    const unsigned char* __restrict__ emask,  // (B,E)
    float* __restrict__ nll)                  // (2048)
{
  const int bm = blockIdx.x;                 // rows bm*16 .. +16
  const int tid = threadIdx.x, lane = tid & 63, wv = tid >> 6;

  __shared__ unsigned short A[16][776];      // 24.8 KB ent rows (padded)
  __shared__ float lg[16][520];              // 33.3 KB logits (padded)
  __shared__ float invl[16];

  if (tid < 16) invl[tid] = 1.0f / (float)elen[bm * 16 + tid];
  __syncthreads();

  // ---- finalize: sum 4 bf16 partial planes, /len, -> LDS A (bf16) ----
  {
    constexpr size_t PSu = (size_t)Bn * En * Hn / 2;
    const unsigned int* src =
        reinterpret_cast<const unsigned int*>(entp) + (size_t)bm * 16 * (Hn / 2);
    for (int idx = tid; idx < 16 * (Hn / 2); idx += 256) {
      const int row = idx / (Hn / 2), u = idx - row * (Hn / 2);
      float lo = 0.f, hi = 0.f;
      #pragma unroll
      for (int p = 0; p < SCH; ++p) {
        const unsigned int v = src[idx + p * PSu];
        lo += bflo(v);
        hi += bfhi(v);
      }
      const float iv = invl[row];
      *reinterpret_cast<unsigned int*>(&A[row][2 * u]) =
          f2bf(lo * iv) | (f2bf(hi * iv) << 16);
    }
  }
  __syncthreads();

  // ---- GEMM 16x512: wave wv owns cols [wv*128, wv*128+128) ----
  const int rl = lane & 15, q = lane >> 4, kr = q * 8;
  const int colBase = wv * 128;
  f32x4 acc[8] = {};
  for (int k0 = 0; k0 < Hn; k0 += 32) {
    const bf16x8 af = *reinterpret_cast<const bf16x8*>(&A[rl][k0 + kr]);
    #pragma unroll
    for (int ni = 0; ni < 8; ++ni) {
      const int c = colBase + ni * 16 + rl;
      const bf16x8 bfr = *reinterpret_cast<const bf16x8*>(
          wbf + (size_t)c * Hn + k0 + kr);
      acc[ni] = __builtin_amdgcn_mfma_f32_16x16x32_bf16(af, bfr, acc[ni], 0, 0, 0);
    }
  }

  // ---- logits -> LDS (C/D layout: col=lane&15, row=q*4+r) ----
  {
    const int rg = q * 4;
    #pragma unroll
    for (int ni = 0; ni < 8; ++ni)
      #pragma unroll
      for (int r = 0; r < 4; ++r)
        lg[rg + r][colBase + ni * 16 + rl] = acc[ni][r];
  }
  __syncthreads();

  // ---- CE: wave wv handles rows wv*4 .. wv*4+4 ----
  #pragma unroll
  for (int j = 0; j < 4; ++j) {
    const int r = wv * 4 + j;
    const int be = bm * 16 + r;
    if (emask[be]) {
      float mx = -3.4e38f;
      for (int i = lane; i < Cn; i += 64) mx = fmaxf(mx, lg[r][i] + bv[i]);
      #pragma unroll
      for (int o = 32; o; o >>= 1) mx = fmaxf(mx, __shfl_xor(mx, o, 64));
      float sm = 0.f;
      for (int i = lane; i < Cn; i += 64) sm += __expf(lg[r][i] + bv[i] - mx);
      #pragma unroll
      for (int o = 32; o; o >>= 1) sm += __shfl_xor(sm, o, 64);
      if (lane == 0) {
        const int tg = attr[be];
        nll[be] = mx + logf(sm) - (lg[r][tg] + bv[tg]);
      }
    } else if (lane == 0) {
      nll[be] = 0.f;
    }
  }
}

// ---------------------------------------------------------------------------
// Kernel 3: deterministic final reduction.
// ---------------------------------------------------------------------------
__global__ __launch_bounds__(256) void reduce_k(
    const float* __restrict__ nll,
    const unsigned char* __restrict__ emask,
    float* __restrict__ out)
{
  const int tid = threadIdx.x;
  float s = 0.f, c = 0.f;
  for (int i = tid; i < Bn * En; i += 256) {
    s += nll[i];
    c += (float)emask[i];
  }
  #pragma unroll
  for (int o = 32; o; o >>= 1) {
    s += __shfl_xor(s, o, 64);
    c += __shfl_xor(c, o, 64);
  }
  __shared__ float ws_[4], wc_[4];
  const int wave = tid >> 6, lane = tid & 63;
  if (lane == 0) { ws_[wave] = s; wc_[wave] = c; }
  __syncthreads();
  if (tid == 0) {
    out[0] = (ws_[0] + ws_[1] + ws_[2] + ws_[3]) /
             (wc_[0] + wc_[1] + wc_[2] + wc_[3]);
  }
}

// ---------------------------------------------------------------------------
extern "C" void kernel_launch(void* const* d_in, const int* in_sizes, int n_in,
                              void* d_out, int out_size, void* d_ws, size_t ws_size,
                              hipStream_t stream) {
  const float* hidden        = (const float*)d_in[0];
  const int* attr            = (const int*)d_in[3];
  const int* el              = (const int*)d_in[4];
  const int* elen            = (const int*)d_in[5];
  const unsigned char* emask = (const unsigned char*)d_in[6];
  const float* Wm            = (const float*)d_in[7];
  const float* bv            = (const float*)d_in[8];

  unsigned short* wbf = (unsigned short*)d_ws;              // 512*768 bf16
  float* nll = (float*)(wbf + (size_t)NP * Hn);             // 2048 f32
  unsigned int* pk2buf = (unsigned int*)(nll + Bn * En);    // B*4*S u32
  unsigned short* entp =
      (unsigned short*)(pk2buf + (size_t)Bn * 4 * Sn);      // SCH*2048*768 bf16

  hipLaunchKernelGGL(pack_k, dim3(1024), dim3(256), 0, stream,
                     el, Wm, pk2buf, wbf);
  hipLaunchKernelGGL(pool_k, dim3(Bn, Hn / PBN, SCH), dim3(256), 0, stream,
                     hidden, pk2buf, entp);
  hipLaunchKernelGGL(tail16_k, dim3(Bn * En / 16), dim3(256), 0, stream,
                     entp, elen, wbf, bv, attr, emask, nll);
  hipLaunchKernelGGL(reduce_k, dim3(1), dim3(256), 0, stream,
                     nll, emask, (float*)d_out);
}

// Round 15
// 62.779 us; speedup vs baseline: 3.5780x; 1.1114x over previous
//
#include <hip/hip_runtime.h>
#include <hip/hip_bf16.h>
#include <cstdint>
#include <cstddef>

// Problem constants: B=16, S=2048, E=128, H=768, C=457
constexpr int Bn = 16, Sn = 2048, En = 128, Hn = 768, Cn = 457;
constexpr int NP = 512;                 // padded class dim for logits GEMM
using f32x4  = __attribute__((ext_vector_type(4))) float;
using bf16x8 = __attribute__((ext_vector_type(8))) short;

static __device__ inline unsigned int f2bf(float x) {
  __hip_bfloat16 b = __float2bfloat16(x);
  return (unsigned int)*reinterpret_cast<unsigned short*>(&b);
}
static __device__ inline float bflo(unsigned int u) {
  unsigned int v = u << 16;
  return *reinterpret_cast<float*>(&v);
}
static __device__ inline float bfhi(unsigned int u) {
  unsigned int v = u & 0xFFFF0000u;
  return *reinterpret_cast<float*>(&v);
}

// LDS-only barrier (rule #18 fencing).
#define LGKM_BAR()                                            \
  do {                                                        \
    asm volatile("s_waitcnt lgkmcnt(0)" ::: "memory");        \
    __builtin_amdgcn_sched_barrier(0);                        \
    __builtin_amdgcn_s_barrier();                             \
    __builtin_amdgcn_sched_barrier(0);                        \
  } while (0)

// ---------------------------------------------------------------------------
// Kernel 0: bit-pack entities_list (word-major pk2[b][w][s]) + piggybacked
// W f32->bf16 cast (blocks 0..511 also cast one W row; rows >= 457 zeroed).
// ---------------------------------------------------------------------------
__global__ __launch_bounds__(256) void pack_k(
    const int* __restrict__ el, const float* __restrict__ Wm,
    unsigned int* __restrict__ pk2, unsigned short* __restrict__ wbf)
{
  const int l = threadIdx.x & 63;
  const int gw = blockIdx.x * 4 + (threadIdx.x >> 6);   // 4096 waves
  #pragma unroll 8
  for (int j = 0; j < 8; ++j) {
    const int tok = gw * 8 + j;                         // 0 .. 32767
    const int b = tok >> 11, s = tok & 2047;
    const int v0 = el[(size_t)tok * 128 + l];
    const int v1 = el[(size_t)tok * 128 + 64 + l];
    const unsigned long long b0 = __ballot(v0 != 0);
    const unsigned long long b1 = __ballot(v1 != 0);
    if (l == 0) {
      unsigned int* p = pk2 + (size_t)b * 4 * Sn + s;
      p[0]          = (unsigned int)b0;
      p[Sn]         = (unsigned int)(b0 >> 32);
      p[2 * Sn]     = (unsigned int)b1;
      p[3 * Sn]     = (unsigned int)(b1 >> 32);
    }
  }
  // piggyback: W cast, one row per block (blocks 0..511)
  const int c = blockIdx.x;
  if (c < NP) {
    unsigned int* dst = reinterpret_cast<unsigned int*>(wbf) + (size_t)c * (Hn / 2);
    for (int t = threadIdx.x; t < Hn / 2; t += 256) {
      unsigned int o = 0u;
      if (c < Cn) {
        const float* wp = Wm + (size_t)c * Hn + 2 * t;
        o = f2bf(wp[0]) | (f2bf(wp[1]) << 16);
      }
      dst[t] = o;
    }
  }
}

// ---------------------------------------------------------------------------
// Kernel 1: pooling bmm.  [r12 exact: PBN=32, 256 thr (4 waves 2x2), 1536
// blocks = 6/CU, PBK=64, lgkm-only barriers, depth-2 reg prefetch,
// in-register A-synth from packed bits, bf16 partials per slice]
// ---------------------------------------------------------------------------
constexpr int PBN = 32, PBK2 = 64, PLD2 = 72;   // Bs row stride 144B
constexpr int SCH = 4, SLEN = Sn / SCH, PNK2 = SLEN / PBK2;   // 8 steps
__global__ __launch_bounds__(256, 6) void pool_k(
    const float* __restrict__ hidden,       // (B,S,H)
    const unsigned int* __restrict__ pk2,   // (B,4,S) packed membership
    unsigned short* __restrict__ entp)      // (SCH, B*E, H) bf16 partials
{
  const int b = blockIdx.x, n0 = blockIdx.y * PBN, sc = blockIdx.z;
  const int s0 = sc * SLEN;
  const int tid = threadIdx.x, l = tid & 63, wv = tid >> 6;  // 4 waves
  const int wm = wv >> 1, wn = wv & 1;                       // 2 x 2

  __shared__ unsigned short Bs[2][PBN][PLD2];  // 9.2 KB  (h x s)
  __shared__ unsigned int   PK2[4 * SLEN];     // 8 KB (word-major slice)

  {
    const int w = tid >> 6, off = (tid & 63) * 8;
    const unsigned int* srcp =
        pk2 + (size_t)b * 4 * Sn + (size_t)w * Sn + s0 + off;
    *reinterpret_cast<uint4*>(&PK2[w * SLEN + off]) =
        *reinterpret_cast<const uint4*>(srcp);
    *reinterpret_cast<uint4*>(&PK2[w * SLEN + off + 4]) =
        *reinterpret_cast<const uint4*>(srcp + 4);
  }

  const float* hb = hidden + ((size_t)b * Sn + s0) * Hn + n0;
  const int g = wv * 2 + (l >> 5), col = l & 31;   // 8 token-groups x 32 cols

  auto loadh = [&](int kk, float (&f)[8]) {
    const int sb = kk * PBK2 + g * 8;
    #pragma unroll
    for (int i = 0; i < 8; ++i)
      f[i] = hb[(size_t)(sb + i) * Hn + col];
  };

  auto stage_b = [&](int bsel, const float (&f)[8]) {
    uint2 d0, d1;
    d0.x = f2bf(f[0]) | (f2bf(f[1]) << 16);
    d0.y = f2bf(f[2]) | (f2bf(f[3]) << 16);
    d1.x = f2bf(f[4]) | (f2bf(f[5]) << 16);
    d1.y = f2bf(f[6]) | (f2bf(f[7]) << 16);
    *reinterpret_cast<uint2*>(&Bs[bsel][col][g * 8])     = d0;
    *reinterpret_cast<uint2*>(&Bs[bsel][col][g * 8 + 4]) = d1;
  };

  f32x4 acc[4] = {};
  const int rl = l & 15, q = l >> 4, kr = q * 8;

  auto mfma_step = [&](int k, int cur) {
    #pragma unroll
    for (int ks = 0; ks < 2; ++ks) {       // two 32-token sub-steps
      const int sbase = k * PBK2 + ks * 32 + kr;
      const bf16x8 bfr = *reinterpret_cast<const bf16x8*>(
          &Bs[cur][wn * 16 + rl][ks * 32 + kr]);
      #pragma unroll
      for (int mp = 0; mp < 2; ++mp) {     // word shared by mi pair
        const int w = wm * 2 + mp;
        const uint4 u0 = *reinterpret_cast<const uint4*>(&PK2[w * SLEN + sbase]);
        const uint4 u1 = *reinterpret_cast<const uint4*>(&PK2[w * SLEN + sbase + 4]);
        #pragma unroll
        for (int mh = 0; mh < 2; ++mh) {   // mi = mp*2 + mh
          const int bi = mh * 16 + rl;
          bf16x8 afr;
          unsigned int* ap = reinterpret_cast<unsigned int*>(&afr);
          ap[0] = (((u0.x >> bi) & 1u) ? 0x3F80u : 0u) |
                  (((u0.y >> bi) & 1u) ? 0x3F800000u : 0u);
          ap[1] = (((u0.z >> bi) & 1u) ? 0x3F80u : 0u) |
                  (((u0.w >> bi) & 1u) ? 0x3F800000u : 0u);
          ap[2] = (((u1.x >> bi) & 1u) ? 0x3F80u : 0u) |
                  (((u1.y >> bi) & 1u) ? 0x3F800000u : 0u);
          ap[3] = (((u1.z >> bi) & 1u) ? 0x3F80u : 0u) |
                  (((u1.w >> bi) & 1u) ? 0x3F800000u : 0u);
          acc[mp * 2 + mh] = __builtin_amdgcn_mfma_f32_16x16x32_bf16(
              afr, bfr, acc[mp * 2 + mh], 0, 0, 0);
        }
      }
    }
  };

  float pf[3][8];
  loadh(0, pf[0]);
  loadh(1, pf[1]);
  LGKM_BAR();                    // PK2 visible (global loads stay in flight)
  stage_b(0, pf[0]);
  LGKM_BAR();

  #pragma unroll
  for (int k = 0; k < PNK2; ++k) {
    if (k + 2 < PNK2) loadh(k + 2, pf[(k + 2) % 3]);
    mfma_step(k, k & 1);
    if (k + 1 < PNK2) {
      stage_b((k + 1) & 1, pf[(k + 1) % 3]);
      LGKM_BAR();
    }
  }

  unsigned short* dst = entp + (size_t)sc * Bn * En * Hn;
  const int rg = q * 4;
  const int colo = n0 + wn * 16 + rl;
  #pragma unroll
  for (int mi = 0; mi < 4; ++mi) {
    #pragma unroll
    for (int r = 0; r < 4; ++r) {
      const int e = wm * 64 + mi * 16 + rg + r;
      dst[(size_t)(b * En + e) * Hn + colo] = (unsigned short)f2bf(acc[mi][r]);
    }
  }
}

// ---------------------------------------------------------------------------
// Kernel 1b: finalize — sum 4 bf16 partials, /len, cast bf16. 2048 blocks.
// ---------------------------------------------------------------------------
__global__ __launch_bounds__(384) void finalize_k(
    const unsigned short* __restrict__ entp, const int* __restrict__ elen,
    unsigned short* __restrict__ entbf)
{
  const int be = blockIdx.x, t = threadIdx.x;      // 384 threads
  const float inv = 1.0f / (float)elen[be];
  constexpr size_t PSu = (size_t)Bn * En * Hn / 2; // plane stride in uints
  const unsigned int* src =
      reinterpret_cast<const unsigned int*>(entp) + (size_t)be * (Hn / 2) + t;
  float lo = 0.f, hi = 0.f;
  #pragma unroll
  for (int p = 0; p < SCH; ++p) {
    const unsigned int u = src[p * PSu];
    lo += bflo(u);
    hi += bfhi(u);
  }
  const unsigned int out = f2bf(lo * inv) | (f2bf(hi * inv) << 16);
  reinterpret_cast<unsigned int*>(entbf)[(size_t)be * (Hn / 2) + t] = out;
}

// ---------------------------------------------------------------------------
// Kernel 2: logits GEMM, 64x32 tiles, 512 blocks (2/CU).  [r12 exact]
// ---------------------------------------------------------------------------
constexpr int BM = 64, BN = 32, BK = 32, LDP = BK + 24;   // 112B row stride
__global__ __launch_bounds__(256) void gemm_k(
    const unsigned short* __restrict__ A,   // (2048,768) bf16
    const unsigned short* __restrict__ Bm,  // (512,768) bf16 (B^T layout)
    float* __restrict__ Cm)                 // (2048,512) f32
{
  __shared__ unsigned short As[BM][LDP];
  __shared__ unsigned short Bs[BN][LDP];
  const int bm = blockIdx.x, bn = blockIdx.y;
  const int tid = threadIdx.x, lane = tid & 63, wv = tid >> 6;
  const int wm = wv >> 1, wn = wv & 1;          // 2x2 wave grid

  f32x4 acc[2] = {};

  for (int k0 = 0; k0 < Hn; k0 += BK) {
    {
      const int r = tid >> 2, kc = (tid & 3) * 8;
      const unsigned short* src = A + (size_t)(bm * BM + r) * Hn + k0 + kc;
      *reinterpret_cast<ulonglong2*>(&As[r][kc]) =
          *reinterpret_cast<const ulonglong2*>(src);
    }
    if (tid < 128) {
      const int r = tid >> 2, kc = (tid & 3) * 8;
      const unsigned short* src = Bm + (size_t)(bn * BN + r) * Hn + k0 + kc;
      *reinterpret_cast<ulonglong2*>(&Bs[r][kc]) =
          *reinterpret_cast<const ulonglong2*>(src);
    }
    __syncthreads();

    const int kr = (lane >> 4) * 8, rl = lane & 15;
    const bf16x8 bf = *reinterpret_cast<const bf16x8*>(&Bs[wn * 16 + rl][kr]);
    #pragma unroll
    for (int mi = 0; mi < 2; ++mi) {
      const bf16x8 af =
          *reinterpret_cast<const bf16x8*>(&As[wm * 32 + mi * 16 + rl][kr]);
      acc[mi] = __builtin_amdgcn_mfma_f32_16x16x32_bf16(af, bf, acc[mi], 0, 0, 0);
    }
    __syncthreads();
  }

  const int cl = lane & 15, rg = (lane >> 4) * 4;
  const int col = bn * BN + wn * 16 + cl;
  #pragma unroll
  for (int mi = 0; mi < 2; ++mi) {
    #pragma unroll
    for (int r = 0; r < 4; ++r) {
      const int row = bm * BM + wm * 32 + mi * 16 + rg + r;
      Cm[(size_t)row * NP + col] = acc[mi][r];
    }
  }
}

// ---------------------------------------------------------------------------
// Kernel 3: CE per entity (one wave each; 4 waves/block). Bias added here.
// ---------------------------------------------------------------------------
__global__ __launch_bounds__(256) void ce_k(
    const float* __restrict__ logits,        // (2048,512)
    const float* __restrict__ bv,            // (457)
    const int* __restrict__ attr,            // (B,E)
    const unsigned char* __restrict__ emask, // (B,E)
    float* __restrict__ nll)                 // (2048)
{
  const int wv = threadIdx.x >> 6, lane = threadIdx.x & 63;
  const int be = blockIdx.x * 4 + wv;
  if (!emask[be]) { if (lane == 0) nll[be] = 0.f; return; }
  const float* row = logits + (size_t)be * NP;

  float mx = -3.4e38f;
  for (int i = lane; i < Cn; i += 64) mx = fmaxf(mx, row[i] + bv[i]);
  #pragma unroll
  for (int o = 32; o; o >>= 1) mx = fmaxf(mx, __shfl_xor(mx, o, 64));
  float sm = 0.f;
  for (int i = lane; i < Cn; i += 64) sm += __expf(row[i] + bv[i] - mx);
  #pragma unroll
  for (int o = 32; o; o >>= 1) sm += __shfl_xor(sm, o, 64);
  if (lane == 0) {
    const int tg = attr[be];
    nll[be] = mx + logf(sm) - (row[tg] + bv[tg]);
  }
}

// ---------------------------------------------------------------------------
// Kernel 4: deterministic final reduction.
// ---------------------------------------------------------------------------
__global__ __launch_bounds__(256) void reduce_k(
    const float* __restrict__ nll,
    const unsigned char* __restrict__ emask,
    float* __restrict__ out)
{
  const int tid = threadIdx.x;
  float s = 0.f, c = 0.f;
  for (int i = tid; i < Bn * En; i += 256) {
    s += nll[i];
    c += (float)emask[i];
  }
  #pragma unroll
  for (int o = 32; o; o >>= 1) {
    s += __shfl_xor(s, o, 64);
    c += __shfl_xor(c, o, 64);
  }
  __shared__ float ws_[4], wc_[4];
  const int wave = tid >> 6, lane = tid & 63;
  if (lane == 0) { ws_[wave] = s; wc_[wave] = c; }
  __syncthreads();
  if (tid == 0) {
    out[0] = (ws_[0] + ws_[1] + ws_[2] + ws_[3]) /
             (wc_[0] + wc_[1] + wc_[2] + wc_[3]);
  }
}

// ---------------------------------------------------------------------------
extern "C" void kernel_launch(void* const* d_in, const int* in_sizes, int n_in,
                              void* d_out, int out_size, void* d_ws, size_t ws_size,
                              hipStream_t stream) {
  const float* hidden        = (const float*)d_in[0];
  const int* attr            = (const int*)d_in[3];
  const int* el              = (const int*)d_in[4];
  const int* elen            = (const int*)d_in[5];
  const unsigned char* emask = (const unsigned char*)d_in[6];
  const float* Wm            = (const float*)d_in[7];
  const float* bv            = (const float*)d_in[8];

  unsigned short* entbf = (unsigned short*)d_ws;            // 2048*768 bf16
  unsigned short* wbf   = entbf + (size_t)Bn * En * Hn;     // 512*768 bf16
  float* logits = (float*)(wbf + (size_t)NP * Hn);          // 2048*512 f32
  float* nll    = logits + (size_t)Bn * En * NP;            // 2048 f32
  unsigned int* pk2buf = (unsigned int*)(nll + Bn * En);    // B*4*S u32
  unsigned short* entp =
      (unsigned short*)(pk2buf + (size_t)Bn * 4 * Sn);      // SCH*2048*768 bf16

  hipLaunchKernelGGL(pack_k, dim3(1024), dim3(256), 0, stream,
                     el, Wm, pk2buf, wbf);
  hipLaunchKernelGGL(pool_k, dim3(Bn, Hn / PBN, SCH), dim3(256), 0, stream,
                     hidden, pk2buf, entp);
  hipLaunchKernelGGL(finalize_k, dim3(Bn * En), dim3(384), 0, stream,
                     entp, elen, entbf);
  hipLaunchKernelGGL(gemm_k, dim3(Bn * En / BM, NP / BN), dim3(256), 0, stream,
                     entbf, wbf, logits);
  hipLaunchKernelGGL(ce_k, dim3(Bn * En / 4), dim3(256), 0, stream,
                     logits, bv, attr, emask, nll);
  hipLaunchKernelGGL(reduce_k, dim3(1), dim3(256), 0, stream,
                     nll, emask, (float*)d_out);
}